// Round 1
// baseline (68.318 us; speedup 1.0000x reference)
//
#include <hip/hip_runtime.h>

// Problem constants (from reference): B=4, C=128, H=64, W=64, L=16, K=64, CD=8.
// C == L*CD. HW = H*W = 4096.
#define Bn   4
#define Cn   128
#define HWn  4096
#define Ln   16
#define Kn   64
#define CDn  8
#define QUANT_ELEMS (Bn * Cn * HWn)   // 2,097,152

// One thread handles one (b, l, pixel) slot:
//   - loads the 8 channels z[b, l*8+d, pix] (coalesced across lanes: lanes vary pix)
//   - computes squared L2 distance to each of the 64 codes for latent slot l
//     (argmin over sqrt(d2) == argmin over d2; sqrt skipped)
//   - writes the winning code into out NCHW (coalesced) and the index
//     (as float, since the harness reads the whole out buffer as fp32).
// Straight-through estimator: forward value == hard_symbols, so softmax /
// soft_symbols are skipped entirely (diff is one fp32 rounding, << threshold).
__global__ __launch_bounds__(256)
void soft_to_hard_encoder_kernel(const float* __restrict__ z,
                                 const float* __restrict__ codes,
                                 float* __restrict__ out) {
    __shared__ float sc[Kn * CDn];  // 64 codes x 8 dims for this block's l (2 KB)

    // blockIdx.x = ((b*Ln + l) * 16) + pixblock ; 16 blocks of 256 pix per (b,l)
    const int pixblock = blockIdx.x & 15;
    const int bl       = blockIdx.x >> 4;
    const int l        = bl & (Ln - 1);
    const int b        = bl >> 4;
    const int pix      = pixblock * 256 + threadIdx.x;

    // Stage codes[l, :, :] into LDS (512 floats, 2 per thread).
    #pragma unroll
    for (int i = threadIdx.x; i < Kn * CDn; i += 256)
        sc[i] = codes[l * Kn * CDn + i];
    __syncthreads();

    // Load this slot's 8-dim latent vector. Channel c = l*8 + d; address
    // ((b*Cn + c) * HWn + pix) is consecutive across lanes -> coalesced.
    float hz[CDn];
    #pragma unroll
    for (int d = 0; d < CDn; ++d)
        hz[d] = z[(size_t)(b * Cn + l * CDn + d) * HWn + pix];

    // Argmin over 64 codes; strict < keeps the first (lowest k) on ties,
    // matching np.argmin semantics.
    float best = 3.402823466e+38f;
    int bidx = 0;
    #pragma unroll 4
    for (int k = 0; k < Kn; ++k) {
        float s = 0.0f;
        #pragma unroll
        for (int d = 0; d < CDn; ++d) {
            float df = hz[d] - sc[k * CDn + d];
            s = fmaf(df, df, s);
        }
        if (s < best) { best = s; bidx = k; }
    }

    // Hard symbols back to NCHW (coalesced per d).
    #pragma unroll
    for (int d = 0; d < CDn; ++d)
        out[(size_t)(b * Cn + l * CDn + d) * HWn + pix] = sc[bidx * CDn + d];

    // idxes layout (b,h,w,l): offset after the quantized block; stored as float.
    out[QUANT_ELEMS + (size_t)(b * HWn + pix) * Ln + l] = (float)bidx;
}

extern "C" void kernel_launch(void* const* d_in, const int* in_sizes, int n_in,
                              void* d_out, int out_size, void* d_ws, size_t ws_size,
                              hipStream_t stream) {
    const float* z     = (const float*)d_in[0];  // (4,128,64,64) fp32
    const float* codes = (const float*)d_in[1];  // (16,64,8) fp32
    float* out         = (float*)d_out;          // quantized (2,097,152) + idxes (262,144)

    const int total_threads = Bn * Ln * HWn;     // 262,144
    const int blocks = total_threads / 256;      // 1024
    soft_to_hard_encoder_kernel<<<blocks, 256, 0, stream>>>(z, codes, out);
}